// Round 4
// baseline (6090.933 us; speedup 1.0000x reference)
//
#include <hip/hip_runtime.h>
#include <stdint.h>
#include <stddef.h>

// LSTM_63488206569533: B=128, T=1024, I=256, H=512, fp32 in/out.
// Persistent kernel: 256 WGs (8 batch-groups x 32 unit-slices), one per CU.
// Each WG: 16 batches x 16 hidden units; K = 768 (x 256 | h 512).
// W rows live in MFMA B-fragment registers (bf16).
// R4: TAG-IN-BAND h exchange -- each h entry is u64 {tag=t+1, 2xbf16}; the
//     consumer retry-loads data until tags match (ONE LLC round trip replaces
//     store-drain -> flag -> poll -> load). Wave-local gate mapping (each wave
//     owns 4 gates x 4 units) kills the gate-LDS barrier; x-projection for
//     t+1 is precomputed in the h-store shadow. 2 barriers/step.

#define Bn    128
#define Tn    1024
#define In    256
#define Hn    512
#define PM    8     // batch groups
#define PN    32    // unit slices
#define BPW   16    // batches per WG
#define APAD  776   // padded A row length in bf16 elems
#define APAD32 388  // same in dwords

typedef float  f4  __attribute__((ext_vector_type(4)));
typedef short  s8  __attribute__((ext_vector_type(8)));
typedef unsigned int u32;
typedef unsigned long long u64;
typedef u32 u32x4 __attribute__((ext_vector_type(4)));

static __device__ __forceinline__ short f2bf(float f) {
  union { float f; unsigned u; } v; v.f = f;
  unsigned u = v.u;
  return (short)((u + 0x7FFFu + ((u >> 16) & 1u)) >> 16);  // RNE
}

__global__ __launch_bounds__(256, 1)
void lstm_persist(const float* __restrict__ x,
                  const float* __restrict__ W_ih,
                  const float* __restrict__ W_hh,
                  const float* __restrict__ b_ih,
                  const float* __restrict__ b_hh,
                  const float* __restrict__ fc_w,
                  const float* __restrict__ fc_b,
                  float* __restrict__ out,
                  u64* __restrict__ hbuf)   // [2][Bn][256] tagged entries
{
  const int tid  = threadIdx.x;
  const int wave = tid >> 6;
  const int lane = tid & 63;
  const int n16  = lane & 15;   // MFMA col (B) / A row (batch) index
  const int q    = lane >> 4;   // MFMA quad
  const int bg   = blockIdx.x & 7;   // batch group
  const int ns   = blockIdx.x >> 3;  // unit slice 0..31

  __shared__ short A_lds[16 * APAD];   // [batch 16][k 768(+pad)] bf16

  // ---- B-fragment mapping (wave-local gates): col c=n16 -> gate g=c>>2,
  // unit uu=c&3; this wave covers units ns*16 + wave*4 + (0..3), all 4 gates.
  const int uu   = n16 & 3;
  const int gsel = n16 >> 2;                       // batch sub-row of my cell
  const int ug_l = ns * 16 + wave * 4 + uu;        // my cell's global unit
  const int bat_l = bg * BPW + q * 4 + gsel;       // my cell's global batch

  s8 bfrag[24];
  {
    const int grow = gsel /*==g for B rows? no:*/ ;
    (void)grow;
    const int g    = n16 >> 2;
    const int wrow = g * Hn + ug_l;                // gate-row in [0,4H)
#pragma unroll
    for (int kk = 0; kk < 24; ++kk) {
      const float* p = (kk < 8)
        ? (W_ih + (size_t)wrow * In + kk * 32 + q * 8)
        : (W_hh + (size_t)wrow * Hn + (kk - 8) * 32 + q * 8);
      f4 lo = ((const f4*)p)[0];
      f4 hi = ((const f4*)p)[1];
      s8 b;
      b[0]=f2bf(lo[0]); b[1]=f2bf(lo[1]); b[2]=f2bf(lo[2]); b[3]=f2bf(lo[3]);
      b[4]=f2bf(hi[0]); b[5]=f2bf(hi[1]); b[6]=f2bf(hi[2]); b[7]=f2bf(hi[3]);
      bfrag[kk] = b;
    }
  }

  // NOTE: wrow above uses gate g = n16>>2 and unit ug_l -- but ug_l already
  // encodes uu = n16&3, and gsel is reused for the CELL batch row. The C/D
  // layout: row = q*4+r = batch, col = n16 = (g,uu).

  // ---- cell biases (per lane, for my (bat_l, ug_l) cell) ----
  const float bia = b_ih[ug_l]          + b_hh[ug_l];
  const float bfa = b_ih[Hn   + ug_l]   + b_hh[Hn   + ug_l];
  const float bga = b_ih[2*Hn + ug_l]   + b_hh[2*Hn + ug_l];
  const float boa = b_ih[3*Hn + ug_l]   + b_hh[3*Hn + ug_l];

  // ---- staging mapping: thread (em,en) stages batch em, 16/32-elem chunks
  const int em  = tid >> 4;
  const int en  = tid & 15;
  const int bgl = bg * BPW + em;                   // staged global batch

  const float* xbase = x + (size_t)bgl * Tn * In + en * 16;
  const short* aptr  = A_lds + n16 * APAD + q * 8;

  float creg = 0.f, hreg = 0.f;

  // ---- prologue: stage x_0, compute xacc for t=0 ----
  {
    const f4* xp = (const f4*)(xbase);
    f4 a = xp[0], b = xp[1], c = xp[2], d = xp[3];
    s8 lo, hi;
    lo[0]=f2bf(a[0]); lo[1]=f2bf(a[1]); lo[2]=f2bf(a[2]); lo[3]=f2bf(a[3]);
    lo[4]=f2bf(b[0]); lo[5]=f2bf(b[1]); lo[6]=f2bf(b[2]); lo[7]=f2bf(b[3]);
    hi[0]=f2bf(c[0]); hi[1]=f2bf(c[1]); hi[2]=f2bf(c[2]); hi[3]=f2bf(c[3]);
    hi[4]=f2bf(d[0]); hi[5]=f2bf(d[1]); hi[6]=f2bf(d[2]); hi[7]=f2bf(d[3]);
    s8* dst = (s8*)(A_lds + em * APAD + en * 16);
    dst[0] = lo; dst[1] = hi;
  }
  __syncthreads();
  f4 xacc = {0.f, 0.f, 0.f, 0.f};
#pragma unroll
  for (int kk = 0; kk < 8; ++kk) {
    s8 a = *(const s8*)(aptr + kk * 32);
    xacc = __builtin_amdgcn_mfma_f32_16x16x32_bf16(a, bfrag[kk], xacc, 0, 0, 0);
  }

  for (int t = 0; t < Tn; ++t) {
    f4 accA = xacc;
    f4 accB = {0.f, 0.f, 0.f, 0.f};

    if (t > 0) {
      // ---- tag-checked retry load of h_t (one LLC round trip per attempt)
      const u64* hp = hbuf + (size_t)(t & 1) * (Bn * 256)
                           + (size_t)bgl * 256 + en * 16;
      u64 v0,v1,v2,v3,v4,v5,v6,v7,v8,v9,va,vb,vc,vd,ve,vf;
      const u64 tagc = ((u64)(u32)t) << 32;
      for (;;) {
        v0=__hip_atomic_load(hp+ 0,__ATOMIC_RELAXED,__HIP_MEMORY_SCOPE_AGENT);
        v1=__hip_atomic_load(hp+ 1,__ATOMIC_RELAXED,__HIP_MEMORY_SCOPE_AGENT);
        v2=__hip_atomic_load(hp+ 2,__ATOMIC_RELAXED,__HIP_MEMORY_SCOPE_AGENT);
        v3=__hip_atomic_load(hp+ 3,__ATOMIC_RELAXED,__HIP_MEMORY_SCOPE_AGENT);
        v4=__hip_atomic_load(hp+ 4,__ATOMIC_RELAXED,__HIP_MEMORY_SCOPE_AGENT);
        v5=__hip_atomic_load(hp+ 5,__ATOMIC_RELAXED,__HIP_MEMORY_SCOPE_AGENT);
        v6=__hip_atomic_load(hp+ 6,__ATOMIC_RELAXED,__HIP_MEMORY_SCOPE_AGENT);
        v7=__hip_atomic_load(hp+ 7,__ATOMIC_RELAXED,__HIP_MEMORY_SCOPE_AGENT);
        v8=__hip_atomic_load(hp+ 8,__ATOMIC_RELAXED,__HIP_MEMORY_SCOPE_AGENT);
        v9=__hip_atomic_load(hp+ 9,__ATOMIC_RELAXED,__HIP_MEMORY_SCOPE_AGENT);
        va=__hip_atomic_load(hp+10,__ATOMIC_RELAXED,__HIP_MEMORY_SCOPE_AGENT);
        vb=__hip_atomic_load(hp+11,__ATOMIC_RELAXED,__HIP_MEMORY_SCOPE_AGENT);
        vc=__hip_atomic_load(hp+12,__ATOMIC_RELAXED,__HIP_MEMORY_SCOPE_AGENT);
        vd=__hip_atomic_load(hp+13,__ATOMIC_RELAXED,__HIP_MEMORY_SCOPE_AGENT);
        ve=__hip_atomic_load(hp+14,__ATOMIC_RELAXED,__HIP_MEMORY_SCOPE_AGENT);
        vf=__hip_atomic_load(hp+15,__ATOMIC_RELAXED,__HIP_MEMORY_SCOPE_AGENT);
        u64 bad = (v0^tagc)|(v1^tagc)|(v2^tagc)|(v3^tagc)
                | (v4^tagc)|(v5^tagc)|(v6^tagc)|(v7^tagc)
                | (v8^tagc)|(v9^tagc)|(va^tagc)|(vb^tagc)
                | (vc^tagc)|(vd^tagc)|(ve^tagc)|(vf^tagc);
        if (!(u32)(bad >> 32)) break;   // all 16 tags == t
      }
      // stage data dwords (each = 2 packed bf16, units en*32+2i, +1)
      u32x4* d4 = (u32x4*)((u32*)A_lds + em * APAD32 + 128 + en * 16);
      u32x4 w0 = { (u32)v0, (u32)v1, (u32)v2, (u32)v3 };
      u32x4 w1 = { (u32)v4, (u32)v5, (u32)v6, (u32)v7 };
      u32x4 w2 = { (u32)v8, (u32)v9, (u32)va, (u32)vb };
      u32x4 w3 = { (u32)vc, (u32)vd, (u32)ve, (u32)vf };
      d4[0] = w0; d4[1] = w1; d4[2] = w2; d4[3] = w3;
    }

    __syncthreads();   // B1: h staging visible (t>0); guards x restage at t==0

    if (t > 0) {
#pragma unroll
      for (int kk = 8; kk < 24; ++kk) {
        s8 a = *(const s8*)(aptr + kk * 32);
        if (kk & 1) accB = __builtin_amdgcn_mfma_f32_16x16x32_bf16(a, bfrag[kk], accB, 0, 0, 0);
        else        accA = __builtin_amdgcn_mfma_f32_16x16x32_bf16(a, bfrag[kk], accA, 0, 0, 0);
      }
    }

    float acc4[4];
#pragma unroll
    for (int r = 0; r < 4; ++r) acc4[r] = accA[r] + accB[r];

    // ---- wave-local 4x4 gate transpose: lane (q,c) -> cell (q*4+gsel, uu)
    const int basel = (lane & 0x30) | uu;    // (q, gate=0, uu)
    float zi = 0.f, zf = 0.f, zg = 0.f, zo = 0.f;
#pragma unroll
    for (int r = 0; r < 4; ++r) {
      float t0 = __shfl(acc4[r], basel,      64);
      float t1 = __shfl(acc4[r], basel + 4,  64);
      float t2 = __shfl(acc4[r], basel + 8,  64);
      float t3 = __shfl(acc4[r], basel + 12, 64);
      if (gsel == r) { zi = t0; zf = t1; zg = t2; zo = t3; }
    }
    zi += bia; zf += bfa; zg += bga; zo += boa;

    float gi = 1.f / (1.f + __expf(-zi));
    float gf = 1.f / (1.f + __expf(-zf));
    float gg = 2.f / (1.f + __expf(-2.f * zg)) - 1.f;
    float go = 1.f / (1.f + __expf(-zo));
    creg = gf * creg + gi * gg;
    float tc = 2.f / (1.f + __expf(-2.f * creg)) - 1.f;
    hreg = go * tc;

    // ---- post h_{t+1}: tagged u64, single atomic 8B store, no drain/flag
    if (t + 1 < Tn) {
      u32 hb = (u32)(unsigned short)f2bf(hreg);
      u32 ob = (u32)__shfl_xor((int)hb, 1, 64);   // partner unit (uu^1)
      if (!(uu & 1)) {
        u64 entry = (((u64)(u32)(t + 1)) << 32) | (hb | (ob << 16));
        u64* hw = hbuf + (size_t)((t + 1) & 1) * (Bn * 256)
                       + (size_t)bat_l * 256 + (ug_l >> 1);
        __hip_atomic_store(hw, entry, __ATOMIC_RELAXED, __HIP_MEMORY_SCOPE_AGENT);
      }
      // ---- in the store shadow: stage x_{t+1} and precompute xacc
      {
        const f4* xp = (const f4*)(xbase + (size_t)(t + 1) * In);
        f4 a = xp[0], b = xp[1], c = xp[2], d = xp[3];
        s8 lo, hi;
        lo[0]=f2bf(a[0]); lo[1]=f2bf(a[1]); lo[2]=f2bf(a[2]); lo[3]=f2bf(a[3]);
        lo[4]=f2bf(b[0]); lo[5]=f2bf(b[1]); lo[6]=f2bf(b[2]); lo[7]=f2bf(b[3]);
        hi[0]=f2bf(c[0]); hi[1]=f2bf(c[1]); hi[2]=f2bf(c[2]); hi[3]=f2bf(c[3]);
        hi[4]=f2bf(d[0]); hi[5]=f2bf(d[1]); hi[6]=f2bf(d[2]); hi[7]=f2bf(d[3]);
        s8* dst = (s8*)(A_lds + em * APAD + en * 16);
        dst[0] = lo; dst[1] = hi;
      }
      __syncthreads();   // B3: x_{t+1} staged; also orders next h restage
      xacc[0] = 0.f; xacc[1] = 0.f; xacc[2] = 0.f; xacc[3] = 0.f;
#pragma unroll
      for (int kk = 0; kk < 8; ++kk) {
        s8 a = *(const s8*)(aptr + kk * 32);
        xacc = __builtin_amdgcn_mfma_f32_16x16x32_bf16(a, bfrag[kk], xacc, 0, 0, 0);
      }
    }
  }

  // ---- epilogue: out[b] = sum_u hT[b,u] * fc_w[u] + fc_b ----
  float partial = hreg * fc_w[ug_l];
  partial += __shfl_xor(partial, 1, 64);   // reduce over uu (4 units/wave)
  partial += __shfl_xor(partial, 2, 64);
  if (uu == 0) {
    if (ns == 0 && wave == 0) partial += fc_b[0];  // once per batch
    atomicAdd(&out[bat_l], partial);
  }
}

extern "C" void kernel_launch(void* const* d_in, const int* in_sizes, int n_in,
                              void* d_out, int out_size, void* d_ws, size_t ws_size,
                              hipStream_t stream) {
  const float* x    = (const float*)d_in[0];
  const float* W_ih = (const float*)d_in[1];
  const float* W_hh = (const float*)d_in[2];
  const float* b_ih = (const float*)d_in[3];
  const float* b_hh = (const float*)d_in[4];
  const float* fc_w = (const float*)d_in[5];
  const float* fc_b = (const float*)d_in[6];
  float* out = (float*)d_out;

  u64* hbuf = (u64*)d_ws;   // 2 x 128 x 256 x 8 B = 512 KB tagged h entries
  // No init needed: 0xAA poison never matches a tag in [1, 1024).

  hipMemsetAsync(d_out, 0, Bn * sizeof(float), stream);  // atomics accumulate

  lstm_persist<<<dim3(PM * PN), dim3(256), 0, stream>>>(
      x, W_ih, W_hh, b_ih, b_hh, fc_w, fc_b, out, hbuf);
}